// Round 11
// baseline (1661.328 us; speedup 1.0000x reference)
//
#include <hip/hip_runtime.h>
#include <math.h>

#define HID 51
#define TMAIN 1024
#define FUT 64
#define TT (TMAIN + FUT)
#define RING 128   // h2 history ring depth (pow2)
#define RPAD 68    // ring row stride in floats (16B-aligned)

typedef float v2f __attribute__((ext_vector_type(2)));

__device__ __forceinline__ float fast_sigmoid(float x) {
  return 1.0f / (1.0f + __expf(-x));
}
__device__ __forceinline__ float fast_tanh(float x) {
  return 1.0f - 2.0f / (__expf(2.0f * x) + 1.0f);
}

// ---- flag-based sync helpers (LDS producer/consumer, no s_barrier) ----
// Writer: data stores -> lgkmcnt(0) -> flag store. Reader: spin on flag,
// compiler fence, then data loads. LDS has no caches; ds ops complete
// in-order per wave, so this ordering is sufficient within a workgroup.
__device__ __forceinline__ void flag_publish(volatile int* f, bool lane0,
                                             int v) {
  asm volatile("s_waitcnt lgkmcnt(0)" ::: "memory");
  if (lane0) *f = v;
}
__device__ __forceinline__ void wait1(volatile int* f, int tgt) {
  while (*f < tgt) __builtin_amdgcn_s_sleep(1);
  asm volatile("" ::: "memory");
}
__device__ __forceinline__ void wait2(volatile int* a, volatile int* b,
                                      int tgt) {
  while (*a < tgt || *b < tgt) __builtin_amdgcn_s_sleep(1);
  asm volatile("" ::: "memory");
}
__device__ __forceinline__ void wait4(volatile int* f, int tgt) {
  while (f[0] < tgt || f[1] < tgt || f[2] < tgt || f[3] < tgt)
    __builtin_amdgcn_s_sleep(1);
  asm volatile("" ::: "memory");
}

// Dual-sequence packed full-K dot (v_pk_fma_f32). a4[12] reads h[48..51]
// (in-bounds of 64/RPAD rows; element 51 junk unused).
__device__ __forceinline__ void dot2x(const float* hA, const float* hB,
                                      const v2f (&w2)[2][25],
                                      const float (&w50)[2],
                                      float (&aA)[2], float (&aB)[2]) {
  const float4* a4 = reinterpret_cast<const float4*>(hA);
  const float4* b4 = reinterpret_cast<const float4*>(hB);
  v2f sA0 = {0.f, 0.f}, sA1 = {0.f, 0.f};
  v2f sB0 = {0.f, 0.f}, sB1 = {0.f, 0.f};
#pragma unroll
  for (int q = 0; q < 12; ++q) {
    float4 av = a4[q];
    float4 bv = b4[q];
    v2f alo = {av.x, av.y}, ahi = {av.z, av.w};
    v2f blo = {bv.x, bv.y}, bhi = {bv.z, bv.w};
    sA0 = __builtin_elementwise_fma(alo, w2[0][2 * q + 0], sA0);
    sB0 = __builtin_elementwise_fma(blo, w2[0][2 * q + 0], sB0);
    sA1 = __builtin_elementwise_fma(alo, w2[1][2 * q + 0], sA1);
    sB1 = __builtin_elementwise_fma(blo, w2[1][2 * q + 0], sB1);
    sA0 = __builtin_elementwise_fma(ahi, w2[0][2 * q + 1], sA0);
    sB0 = __builtin_elementwise_fma(bhi, w2[0][2 * q + 1], sB0);
    sA1 = __builtin_elementwise_fma(ahi, w2[1][2 * q + 1], sA1);
    sB1 = __builtin_elementwise_fma(bhi, w2[1][2 * q + 1], sB1);
  }
  float4 at = a4[12];
  float4 bt = b4[12];
  v2f alo = {at.x, at.y}, blo = {bt.x, bt.y};
  sA0 = __builtin_elementwise_fma(alo, w2[0][24], sA0);
  sB0 = __builtin_elementwise_fma(blo, w2[0][24], sB0);
  sA1 = __builtin_elementwise_fma(alo, w2[1][24], sA1);
  sB1 = __builtin_elementwise_fma(blo, w2[1][24], sB1);
  aA[0] = fmaf(at.z, w50[0], aA[0] + sA0.x + sA0.y);
  aB[0] = fmaf(bt.z, w50[0], aB[0] + sB0.x + sB0.y);
  aA[1] = fmaf(at.z, w50[1], aA[1] + sA1.x + sA1.y);
  aB[1] = fmaf(bt.z, w50[1], aB[1] + sB1.x + sB1.y);
}

// Half-K dual-seq dot; K2 waves' pair 12 uses {h[50],h[51]=0}.
__device__ __forceinline__ void dotH(const float* hA, const float* hB,
                                     const v2f (&w)[2][13],
                                     float (&aA)[2], float (&aB)[2]) {
  const float2* a2 = reinterpret_cast<const float2*>(hA);
  const float2* b2 = reinterpret_cast<const float2*>(hB);
  v2f sA0 = {0.f, 0.f}, sA1 = {0.f, 0.f};
  v2f sB0 = {0.f, 0.f}, sB1 = {0.f, 0.f};
#pragma unroll
  for (int p = 0; p < 13; ++p) {
    float2 av = a2[p], bv = b2[p];
    v2f a = {av.x, av.y}, b = {bv.x, bv.y};
    sA0 = __builtin_elementwise_fma(a, w[0][p], sA0);
    sB0 = __builtin_elementwise_fma(b, w[0][p], sB0);
    sA1 = __builtin_elementwise_fma(a, w[1][p], sA1);
    sB1 = __builtin_elementwise_fma(b, w[1][p], sB1);
  }
  aA[0] = sA0.x + sA0.y;
  aB[0] = sB0.x + sB0.y;
  aA[1] = sA1.x + sA1.y;
  aB[1] = sB1.x + sB1.y;
}

// One block = TWO sequences, 8 waves. R10 lesson: interval(~3060cy) >>
// heaviest chain(~800cy) -> the global barrier convoy is the cost. This
// round: main loop runs BARRIER-FREE on per-wave LDS step-flags:
//   wid0,1 (L1, full Wh1): h1(k);   waits fOther>=k-1, min(f4..7)>=k-4
//   wid4,5 (Wi2 K2+bias2): piK2(j); waits min(f0,1)>=j, min(f2,3)>=j-4
//   wid6,7 (Wi2 K1):       piK1(j); same waits
//   wid2,3 (L2, full Wh2): h2(m);   waits min(f4..7)>=m, fOther>=m-1
//   flush (wid4,5, every 64 j): waits min(f2,3)>=c+63
// Slack: h1 4-deep, piK 4-deep, h2 ring 128-deep. No cyclic waits ->
// no deadlock; waves slide instead of convoying.
// Feedback phase (serial out->x) keeps barrier-based 3-sub-phase code.
__global__ __launch_bounds__(512, 2)
void lstm2_persistent(const float* __restrict__ input,
                      const float* __restrict__ Wi1,
                      const float* __restrict__ Wh1,
                      const float* __restrict__ bi1,
                      const float* __restrict__ bh1,
                      const float* __restrict__ Wi2,
                      const float* __restrict__ Wh2,
                      const float* __restrict__ bi2,
                      const float* __restrict__ bh2,
                      const float* __restrict__ Wlin,
                      const float* __restrict__ blin,
                      float* __restrict__ out) {
  __shared__ __align__(16) float lds_x[2][TMAIN];        // [seq][t]
  __shared__ __align__(16) float lds_h1[4][2][64];       // [par4][seq][u]
  __shared__ __align__(16) float lds_piK1[4][2][4][64];  // [par4][seq][g][u]
  __shared__ __align__(16) float lds_piK2[4][2][4][64];  // [par4][seq][g][u]
  __shared__ __align__(16) float lds_h2h[RING][2][RPAD]; // [slot][seq][u]
  __shared__ __align__(16) float lds_wlin[64];
  __shared__ __align__(16) float lds_outbuf[2][64];      // feedback outputs
  __shared__ float lds_lin[2][2][2];                     // [par][seq][cellw]
  __shared__ float lds_fb[2];                            // out(1023) seed
  __shared__ int lds_flags[8];                           // completed step/wave

  volatile int* vf = (volatile int*)lds_flags;

  const int tid = threadIdx.x;
  const int s0 = blockIdx.x * 2;  // sequence pair
  const int wid = tid >> 6;       // 0..7
  const int lane = tid & 63;
  const int half = lane >> 5;   // 0: gates {i,f}, 1: gates {g,o}
  const int l5 = lane & 31;
  const int base = (wid & 1) * 26;
  const int nu = (wid & 1) ? 25 : 26;
  const bool act = l5 < nu;
  const int u = base + (act ? l5 : 0);  // clamped unit index
  const int g0 = half * 2;
  const int koff = (wid >= 6) ? 0 : 26;  // Wi2 K-half offset
  const int kh = (wid >= 6) ? 0 : 1;     // 0 -> piK1, 1 -> piK2(+bias2)

  // Stage inputs; zero all 4 h1 bufs (elems 51..63 stay 0 forever -> dotH
  // tail-safe); zero ring slot RING-1 (h2(-1)=0); stage wlin; init flags.
  for (int i = tid; i < TMAIN; i += 512) {
    lds_x[0][i] = input[s0 * TMAIN + i];
    lds_x[1][i] = input[(s0 + 1) * TMAIN + i];
  }
  if (tid < 64) {
#pragma unroll
    for (int p = 0; p < 4; ++p) {
      lds_h1[p][0][tid] = 0.0f;
      lds_h1[p][1][tid] = 0.0f;
    }
    lds_wlin[tid] = (tid < HID) ? Wlin[tid] : 0.0f;
  }
  if (tid < 128) lds_h2h[RING - 1][tid >> 6][tid & 63] = 0.0f;
  if (tid < 8) lds_flags[tid] = -1;

  // ---- weights ----
  v2f w2f[2][25];  // full rows (L1 / Wh2 cell waves)
  float w50f[2] = {0.f, 0.f};
  v2f w2h[2][13];  // half rows (Wi2 waves)
  float bias[2] = {0.f, 0.f};
  float wi1g[2] = {0.f, 0.f};
  float wlin_u = 0.0f;
  float cA = 0.0f, cB = 0.0f;  // cell states (L1 in wid01, L2 in wid23)

  if (wid < 4) {
    const float* Wsel = (wid < 2) ? Wh1 : Wh2;
#pragma unroll
    for (int g = 0; g < 2; ++g) {
      const float* row = Wsel + ((g0 + g) * HID + u) * HID;
#pragma unroll
      for (int p = 0; p < 25; ++p) {
        v2f t;
        t.x = row[2 * p + 0];
        t.y = row[2 * p + 1];
        w2f[g][p] = t;
      }
      w50f[g] = row[50];
    }
    if (wid < 2) {
#pragma unroll
      for (int g = 0; g < 2; ++g) {
        bias[g] = bi1[(g0 + g) * HID + u] + bh1[(g0 + g) * HID + u];
        wi1g[g] = Wi1[(g0 + g) * HID + u];
      }
    } else {
      wlin_u = Wlin[u];  // feedback-phase butterfly weight
    }
#pragma unroll
    for (int g = 0; g < 2; ++g) {
#pragma unroll
      for (int p = 0; p < 25; ++p) asm volatile("" : "+v"(w2f[g][p]));
      asm volatile("" : "+v"(w50f[g]), "+v"(bias[g]), "+v"(wi1g[g]));
    }
    asm volatile("" : "+v"(wlin_u));
  } else {
#pragma unroll
    for (int g = 0; g < 2; ++g) {
      const float* row = Wi2 + ((g0 + g) * HID + u) * HID + koff;
      if (koff == 0) {
#pragma unroll
        for (int p = 0; p < 13; ++p) {
          v2f t;
          t.x = row[2 * p + 0];
          t.y = row[2 * p + 1];
          w2h[g][p] = t;
        }
      } else {
#pragma unroll
        for (int p = 0; p < 12; ++p) {
          v2f t;
          t.x = row[2 * p + 0];
          t.y = row[2 * p + 1];
          w2h[g][p] = t;
        }
        v2f t;
        t.x = row[24];  // K=50
        t.y = 0.0f;     // pairs with h1[51] == 0
        w2h[g][12] = t;
      }
    }
    if (kh == 1) {  // K2 waves carry bias2 (folded into piK2 writes)
#pragma unroll
      for (int g = 0; g < 2; ++g)
        bias[g] = bi2[(g0 + g) * HID + u] + bh2[(g0 + g) * HID + u];
    }
#pragma unroll
    for (int g = 0; g < 2; ++g) {
#pragma unroll
      for (int p = 0; p < 13; ++p) asm volatile("" : "+v"(w2h[g][p]));
      asm volatile("" : "+v"(bias[g]));
    }
  }
  const float blin_s = blin[0];

  __syncthreads();  // staging + flag init visible; last barrier before main

  // ================= barrier-free main phase =================
  if (wid < 2) {
    volatile int* fOther = vf + (1 - wid);
    for (int k = 0; k < TMAIN; ++k) {
      wait1(fOther, k - 1);   // other L1 half of h1(k-1)
      wait4(vf + 4, k - 4);   // h1(k-4) consumed -> slot reusable
      float xA = lds_x[0][k], xB = lds_x[1][k];
      float aA[2], aB[2];
#pragma unroll
      for (int g = 0; g < 2; ++g) {
        aA[g] = fmaf(xA, wi1g[g], bias[g]);
        aB[g] = fmaf(xB, wi1g[g], bias[g]);
      }
      dot2x(lds_h1[k & 3][0], lds_h1[k & 3][1], w2f, w50f, aA, aB);
      float pA0 = __shfl_xor(aA[0], 32), pA1 = __shfl_xor(aA[1], 32);
      float pB0 = __shfl_xor(aB[0], 32), pB1 = __shfl_xor(aB[1], 32);
      float giA = half ? pA0 : aA[0], gfA = half ? pA1 : aA[1];
      float ggA = half ? aA[0] : pA0, goA = half ? aA[1] : pA1;
      float giB = half ? pB0 : aB[0], gfB = half ? pB1 : aB[1];
      float ggB = half ? aB[0] : pB0, goB = half ? aB[1] : pB1;
      cA = fast_sigmoid(gfA) * cA + fast_sigmoid(giA) * fast_tanh(ggA);
      cB = fast_sigmoid(gfB) * cB + fast_sigmoid(giB) * fast_tanh(ggB);
      float hA = fast_sigmoid(goA) * fast_tanh(cA);
      float hB = fast_sigmoid(goB) * fast_tanh(cB);
      if (act && half == 0) {
        lds_h1[(k + 1) & 3][0][u] = hA;
        lds_h1[(k + 1) & 3][1][u] = hB;
      }
      flag_publish(vf + wid, lane == 0, k);
    }
  } else if (wid >= 4) {
    const int seq = wid - 4;  // flush seq for wid4,5
    for (int j = 0; j < TMAIN; ++j) {
      wait2(vf + 0, vf + 1, j);      // h1(j) ready
      wait2(vf + 2, vf + 3, j - 4);  // piK(j-4) consumed -> slot reusable
      float aA[2], aB[2];
      dotH(&lds_h1[(j + 1) & 3][0][koff], &lds_h1[(j + 1) & 3][1][koff], w2h,
           aA, aB);
      const int pm = j & 3;
      if (act) {
        if (kh == 1) {
          aA[0] += bias[0];
          aA[1] += bias[1];
          aB[0] += bias[0];
          aB[1] += bias[1];
          lds_piK2[pm][0][g0 + 0][u] = aA[0];
          lds_piK2[pm][0][g0 + 1][u] = aA[1];
          lds_piK2[pm][1][g0 + 0][u] = aB[0];
          lds_piK2[pm][1][g0 + 1][u] = aB[1];
        } else {
          lds_piK1[pm][0][g0 + 0][u] = aA[0];
          lds_piK1[pm][0][g0 + 1][u] = aA[1];
          lds_piK1[pm][1][g0 + 0][u] = aB[0];
          lds_piK1[pm][1][g0 + 1][u] = aB[1];
        }
      }
      flag_publish(vf + wid, lane == 0, j);
      // deferred linear head: one 64-wide chunk per 64 steps (wid4,5)
      if (wid < 6 && (j & 63) == 63) {
        const int c = j - 63;
        wait2(vf + 2, vf + 3, j);  // h2(c..c+63) ready
        const int m = c + lane;
        const float* r = &lds_h2h[m & (RING - 1)][seq][0];
        const float4* r4 = reinterpret_cast<const float4*>(r);
        const float4* w4 = reinterpret_cast<const float4*>(lds_wlin);
        float o0 = 0.f, o1 = 0.f, o2 = 0.f, o3 = 0.f;
#pragma unroll
        for (int q = 0; q < 12; ++q) {
          float4 rv = r4[q];
          float4 wv = w4[q];
          o0 = fmaf(rv.x, wv.x, o0);
          o1 = fmaf(rv.y, wv.y, o1);
          o2 = fmaf(rv.z, wv.z, o2);
          o3 = fmaf(rv.w, wv.w, o3);
        }
        o0 = fmaf(r[48], lds_wlin[48], o0);
        o1 = fmaf(r[49], lds_wlin[49], o1);
        o2 = fmaf(r[50], lds_wlin[50], o2);
        float o = (o0 + o1) + (o2 + o3) + blin_s;
        out[(s0 + seq) * TT + m] = o;
        if (m == TMAIN - 1) lds_fb[seq] = o;  // feedback seed
      }
    }
  } else {  // wid 2,3 : L2 cell
    volatile int* fOther = vf + (5 - wid);
    for (int m = 0; m < TMAIN; ++m) {
      wait4(vf + 4, m);       // piK(m) ready
      wait1(fOther, m - 1);   // other half of h2(m-1)
      const int pm = m & 3;
      float aA[2], aB[2];
      aA[0] = lds_piK1[pm][0][g0 + 0][u] + lds_piK2[pm][0][g0 + 0][u];
      aA[1] = lds_piK1[pm][0][g0 + 1][u] + lds_piK2[pm][0][g0 + 1][u];
      aB[0] = lds_piK1[pm][1][g0 + 0][u] + lds_piK2[pm][1][g0 + 0][u];
      aB[1] = lds_piK1[pm][1][g0 + 1][u] + lds_piK2[pm][1][g0 + 1][u];
      dot2x(&lds_h2h[(m - 1) & (RING - 1)][0][0],
            &lds_h2h[(m - 1) & (RING - 1)][1][0], w2f, w50f, aA, aB);
      float pA0 = __shfl_xor(aA[0], 32), pA1 = __shfl_xor(aA[1], 32);
      float pB0 = __shfl_xor(aB[0], 32), pB1 = __shfl_xor(aB[1], 32);
      float giA = half ? pA0 : aA[0], gfA = half ? pA1 : aA[1];
      float ggA = half ? aA[0] : pA0, goA = half ? aA[1] : pA1;
      float giB = half ? pB0 : aB[0], gfB = half ? pB1 : aB[1];
      float ggB = half ? aB[0] : pB0, goB = half ? aB[1] : pB1;
      cA = fast_sigmoid(gfA) * cA + fast_sigmoid(giA) * fast_tanh(ggA);
      cB = fast_sigmoid(gfB) * cB + fast_sigmoid(giB) * fast_tanh(ggB);
      float hA = fast_sigmoid(goA) * fast_tanh(cA);
      float hB = fast_sigmoid(goB) * fast_tanh(cB);
      if (act && half == 0) {
        lds_h2h[m & (RING - 1)][0][u] = hA;
        lds_h2h[m & (RING - 1)][1][u] = hB;
      }
      flag_publish(vf + wid, lane == 0, m);
    }
  }

  __syncthreads();  // re-converge before the serial feedback phase

  // =============== feedback phase: 3 sub-phases, barriered ==============
  for (int t = TMAIN; t < TT; ++t) {
    float phA[2] = {0.f, 0.f}, phB[2] = {0.f, 0.f};
    // --- A: L1 cell with feedback x; cell waves pre-dot Wh2 @ h2(t-1) ---
    if (wid < 2) {
      float oA, oB;
      if (t == TMAIN) {
        oA = lds_fb[0];
        oB = lds_fb[1];
      } else {
        oA = lds_lin[(t - 1) & 1][0][0] + lds_lin[(t - 1) & 1][0][1] + blin_s;
        oB = lds_lin[(t - 1) & 1][1][0] + lds_lin[(t - 1) & 1][1][1] + blin_s;
        if (lane == 0) {  // buffer future outputs; flushed in epilogue
          if (wid == 0) lds_outbuf[0][t - 1 - TMAIN] = oA;
          else          lds_outbuf[1][t - 1 - TMAIN] = oB;
        }
      }
      float aA[2], aB[2];
#pragma unroll
      for (int g = 0; g < 2; ++g) {
        aA[g] = fmaf(oA, wi1g[g], bias[g]);
        aB[g] = fmaf(oB, wi1g[g], bias[g]);
      }
      dot2x(lds_h1[t & 3][0], lds_h1[t & 3][1], w2f, w50f, aA, aB);
      float pA0 = __shfl_xor(aA[0], 32), pA1 = __shfl_xor(aA[1], 32);
      float pB0 = __shfl_xor(aB[0], 32), pB1 = __shfl_xor(aB[1], 32);
      float giA = half ? pA0 : aA[0], gfA = half ? pA1 : aA[1];
      float ggA = half ? aA[0] : pA0, goA = half ? aA[1] : pA1;
      float giB = half ? pB0 : aB[0], gfB = half ? pB1 : aB[1];
      float ggB = half ? aB[0] : pB0, goB = half ? aB[1] : pB1;
      cA = fast_sigmoid(gfA) * cA + fast_sigmoid(giA) * fast_tanh(ggA);
      cB = fast_sigmoid(gfB) * cB + fast_sigmoid(giB) * fast_tanh(ggB);
      float hA = fast_sigmoid(goA) * fast_tanh(cA);
      float hB = fast_sigmoid(goB) * fast_tanh(cB);
      if (act && half == 0) {
        lds_h1[(t + 1) & 3][0][u] = hA;
        lds_h1[(t + 1) & 3][1][u] = hB;
      }
    } else if (wid < 4) {
      dot2x(&lds_h2h[(t - 1) & (RING - 1)][0][0],
            &lds_h2h[(t - 1) & (RING - 1)][1][0], w2f, w50f, phA, phB);
    }
    __syncthreads();
    // --- B: piK halves from h1(t) ---
    if (wid >= 4) {
      float aA[2], aB[2];
      dotH(&lds_h1[(t + 1) & 3][0][koff], &lds_h1[(t + 1) & 3][1][koff], w2h,
           aA, aB);
      const int pm = t & 3;
      if (act) {
        if (kh == 1) {
          aA[0] += bias[0];
          aA[1] += bias[1];
          aB[0] += bias[0];
          aB[1] += bias[1];
          lds_piK2[pm][0][g0 + 0][u] = aA[0];
          lds_piK2[pm][0][g0 + 1][u] = aA[1];
          lds_piK2[pm][1][g0 + 0][u] = aB[0];
          lds_piK2[pm][1][g0 + 1][u] = aB[1];
        } else {
          lds_piK1[pm][0][g0 + 0][u] = aA[0];
          lds_piK1[pm][0][g0 + 1][u] = aA[1];
          lds_piK1[pm][1][g0 + 0][u] = aB[0];
          lds_piK1[pm][1][g0 + 1][u] = aB[1];
        }
      }
    }
    __syncthreads();
    // --- C: L2 cell + linear head (butterfly on cell waves here) ---
    if (wid >= 2 && wid < 4) {
      const int pm = t & 3;
      float aA[2], aB[2];
      aA[0] = lds_piK1[pm][0][g0 + 0][u] + lds_piK2[pm][0][g0 + 0][u] + phA[0];
      aA[1] = lds_piK1[pm][0][g0 + 1][u] + lds_piK2[pm][0][g0 + 1][u] + phA[1];
      aB[0] = lds_piK1[pm][1][g0 + 0][u] + lds_piK2[pm][1][g0 + 0][u] + phB[0];
      aB[1] = lds_piK1[pm][1][g0 + 1][u] + lds_piK2[pm][1][g0 + 1][u] + phB[1];
      float pA0 = __shfl_xor(aA[0], 32), pA1 = __shfl_xor(aA[1], 32);
      float pB0 = __shfl_xor(aB[0], 32), pB1 = __shfl_xor(aB[1], 32);
      float giA = half ? pA0 : aA[0], gfA = half ? pA1 : aA[1];
      float ggA = half ? aA[0] : pA0, goA = half ? aA[1] : pA1;
      float giB = half ? pB0 : aB[0], gfB = half ? pB1 : aB[1];
      float ggB = half ? aB[0] : pB0, goB = half ? aB[1] : pB1;
      cA = fast_sigmoid(gfA) * cA + fast_sigmoid(giA) * fast_tanh(ggA);
      cB = fast_sigmoid(gfB) * cB + fast_sigmoid(giB) * fast_tanh(ggB);
      float hA = fast_sigmoid(goA) * fast_tanh(cA);
      float hB = fast_sigmoid(goB) * fast_tanh(cB);
      float val = 0.0f;
      if (act) {
        if (half == 0) {
          lds_h2h[t & (RING - 1)][0][u] = hA;
          val = wlin_u * hA;
        } else {
          lds_h2h[t & (RING - 1)][1][u] = hB;
          val = wlin_u * hB;
        }
      }
#pragma unroll
      for (int off = 16; off >= 1; off >>= 1) val += __shfl_xor(val, off);
      if (lane == 0) lds_lin[t & 1][0][wid - 2] = val;
      if (lane == 32) lds_lin[t & 1][1][wid - 2] = val;
    }
    __syncthreads();
  }

  // epilogue: buffer out(TT-1), then flush the 64 future outputs
  if (wid < 2 && lane == 0) {
    float o = lds_lin[(TT - 1) & 1][wid][0] + lds_lin[(TT - 1) & 1][wid][1] +
              blin_s;
    lds_outbuf[wid][63] = o;
  }
  __syncthreads();
  if (wid == 4 || wid == 5) {
    const int seq = wid - 4;
    out[(s0 + seq) * TT + TMAIN + lane] = lds_outbuf[seq][lane];
  }
}

extern "C" void kernel_launch(void* const* d_in, const int* in_sizes, int n_in,
                              void* d_out, int out_size, void* d_ws,
                              size_t ws_size, hipStream_t stream) {
  const float* input = (const float*)d_in[0];
  const float* Wi1 = (const float*)d_in[1];
  const float* Wh1 = (const float*)d_in[2];
  const float* bi1 = (const float*)d_in[3];
  const float* bh1 = (const float*)d_in[4];
  const float* Wi2 = (const float*)d_in[5];
  const float* Wh2 = (const float*)d_in[6];
  const float* bi2 = (const float*)d_in[7];
  const float* bh2 = (const float*)d_in[8];
  const float* Wlin = (const float*)d_in[9];
  const float* blin = (const float*)d_in[10];
  float* out = (float*)d_out;

  const int B = in_sizes[0] / TMAIN;  // 512
  lstm2_persistent<<<B / 2, 512, 0, stream>>>(input, Wi1, Wh1, bi1, bh1, Wi2,
                                              Wh2, bi2, bh2, Wlin, blin, out);
}